// Round 1
// baseline (287.112 us; speedup 1.0000x reference)
//
#include <hip/hip_runtime.h>
#include <stdint.h>
#include <stddef.h>

#define BATCH 16
#define CH    64
#define IH    128
#define IW    128
#define HW    (IH*IW)

// Padded activation layout: [b][yp 0..129][cc 0..1][xp 0..129][cin32]
#define PROW 8320            // shorts per padded row (2*130*32)
#define PB   1081600         // shorts per batch (130*PROW)

typedef __attribute__((ext_vector_type(8))) short short8;
typedef __attribute__((ext_vector_type(4))) short short4v;
typedef __attribute__((ext_vector_type(4))) float f32x4;
typedef __attribute__((ext_vector_type(2))) float f32x2;

__device__ __forceinline__ float bf2f(short s) {
    union { unsigned int u; float f; } v;
    v.u = ((unsigned int)(unsigned short)s) << 16;
    return v.f;
}
__device__ __forceinline__ short f2bf(float f) {
    union { float f; unsigned int u; } v; v.f = f;
    unsigned int r = v.u + 0x7fffu + ((v.u >> 16) & 1u);
    return (short)(r >> 16);
}

// ---------------------------------------------------------------------------
// Zero the halo pads of both padded activation buffers.
// ---------------------------------------------------------------------------
__global__ __launch_bounds__(256) void pad_zero(short* __restrict__ xpad,
                                                short* __restrict__ hpad) {
    int bid = blockIdx.x;
    short* p = ((bid & 1) ? hpad : xpad) + (size_t)(bid >> 1) * PB;
    const short8 z = {0,0,0,0,0,0,0,0};
    #pragma unroll
    for (int i = 0; i < 17; ++i) {
        int s = i * 256 + threadIdx.x;
        if (s >= 4128) break;
        if (s < 2080) {                       // padded rows 0 and 129 (full)
            int row = (s < 1040) ? 0 : 129;
            int o = (s < 1040 ? s : s - 1040) * 8;
            *(short8*)&p[(size_t)row * PROW + o] = z;
        } else {                              // cols 0 and 129 of rows 1..128
            int u = s - 2080;                 // [0,2048)
            int k = u & 3, col = (u >> 2) & 1, cc = (u >> 3) & 1, pr = (u >> 4) + 1;
            *(short8*)&p[(size_t)pr * PROW + cc * 4160 + (col ? 129 * 32 : 0) + k * 8] = z;
        }
    }
}

// ---------------------------------------------------------------------------
// K0a: x NCHW fp32 -> padded NHWC32 bf16 interior (per-(b,y) row, LDS transpose)
// ---------------------------------------------------------------------------
__global__ __launch_bounds__(256) void prep_x(const float* __restrict__ x,
                                              short* __restrict__ xpad) {
    __shared__ float tile[CH * 129];
    const int b = blockIdx.x >> 7;
    const int y = blockIdx.x & 127;
    const int t = threadIdx.x;
    const float* src = x + (size_t)b * CH * HW + (size_t)y * IW;
    #pragma unroll
    for (int i = 0; i < 32; ++i) {
        int lin = i * 256 + t;
        int c = lin >> 7, xx = lin & 127;
        tile[c * 129 + xx] = src[(size_t)c * HW + xx];
    }
    __syncthreads();
    unsigned int* dst = (unsigned int*)(xpad) + (size_t)b * (PB / 2) + (size_t)(y + 1) * (PROW / 2);
    #pragma unroll
    for (int j = 0; j < 16; ++j) {
        int lin = j * 256 + t;
        int c2 = lin & 31, xx = lin >> 5;
        unsigned int lo = (unsigned int)(unsigned short)f2bf(tile[(2 * c2) * 129 + xx]);
        unsigned int hi = (unsigned int)(unsigned short)f2bf(tile[(2 * c2 + 1) * 129 + xx]);
        dst[(c2 >> 4) * 2080 + (xx + 1) * 16 + (c2 & 15)] = lo | (hi << 16);
    }
}

// ---------------------------------------------------------------------------
// K0b: weights fp32 [b][co][ci][3][3] -> bf16 [b][cc][tap][cout][cin32]
// ---------------------------------------------------------------------------
__global__ __launch_bounds__(256) void prep_w(const float* __restrict__ w1,
                                              const float* __restrict__ w2,
                                              short* __restrict__ w1t,
                                              short* __restrict__ w2t) {
    int bid = blockIdx.x;
    const float* src = w1; short* dst = w1t;
    if (bid >= 256) { src = w2; dst = w2t; bid -= 256; }
    int gt = bid * 256 + threadIdx.x;       // (b, cc, cout, ci)
    int ci   = gt & 31;
    int cout = (gt >> 5) & 63;
    int cc   = (gt >> 11) & 1;
    int b    = gt >> 12;
    const float* s = src + ((size_t)(b * 64 + cout)) * 576 + (cc * 32 + ci) * 9;
    short* d = dst + ((size_t)(b * 2 + cc) * 9) * 2048 + cout * 32 + ci;
    #pragma unroll
    for (int tap = 0; tap < 9; ++tap)
        d[tap * 2048] = f2bf(s[tap]);
}

// ---------------------------------------------------------------------------
// Conv: zero-LDS, latency-hiding-by-occupancy implicit GEMM.
// Block = 4 waves = TWO output rows: 64 cout x 128 px each.
// Wave: (wr=wave>>1 -> row y0*2+wr, ph=wave&1 -> px half) = 64 cout x 64 px,
// acc 4x4 f32x4 (64 VGPR). Per (cc,tap) step: 4 A-loads + 4 B-loads feed
// 16 MFMAs (0.5 loads/MFMA, was 0.75). All 4 waves read identical weights
// (L1 hits); the two row-waves share 2 of 3 input rows.
// No barriers, no atomics. grid dim3(64, 16) = 1024 blocks = 4 blocks/CU.
// ---------------------------------------------------------------------------
__global__ __launch_bounds__(256, 4) void conv_kernel(
    const short* __restrict__ in, const short* __restrict__ wt,
    short* __restrict__ out,
    float* __restrict__ part_s, float* __restrict__ part_q) {

    const int b    = blockIdx.y;
    const int t    = threadIdx.x;
    const int lane = t & 63;
    const int wave = t >> 6;
    const int l15  = lane & 15;
    const int q    = lane >> 4;
    const int ph   = wave & 1;               // px half
    const int wr   = wave >> 1;              // which output row of the pair
    const int y0   = (blockIdx.x << 1) + wr; // output row
    const int xb   = ph * 64;

    const short* wgl = wt + (size_t)b * 36864;
    const short* inB = in + (size_t)b * PB;
    const int aoff = l15 * 32 + q * 8;
    const int boff = (xb + l15) * 32 + q * 8;

    const f32x4 zero4 = {0.f, 0.f, 0.f, 0.f};
    f32x4 acc[4][4];
    #pragma unroll
    for (int mi = 0; mi < 4; ++mi)
        #pragma unroll
        for (int ni = 0; ni < 4; ++ni) acc[mi][ni] = zero4;

    #pragma unroll
    for (int cc = 0; cc < 2; ++cc) {
        #pragma unroll
        for (int tap = 0; tap < 9; ++tap) {
            const int dy = tap / 3, dx = tap % 3;
            const short* arow = wgl + (cc * 9 + tap) * 2048 + aoff;
            const short* brow = inB + (size_t)(y0 + dy) * PROW + cc * 4160 + dx * 32 + boff;
            short8 a[4], bb[4];
            #pragma unroll
            for (int mi = 0; mi < 4; ++mi)
                a[mi] = *(const short8*)&arow[mi * 512];
            #pragma unroll
            for (int ni = 0; ni < 4; ++ni)
                bb[ni] = *(const short8*)&brow[ni * 512];
            #pragma unroll
            for (int mi = 0; mi < 4; ++mi)
                #pragma unroll
                for (int ni = 0; ni < 4; ++ni)
                    acc[mi][ni] = __builtin_amdgcn_mfma_f32_16x16x32_bf16(
                        a[mi], bb[ni], acc[mi][ni], 0, 0, 0);
        }
    }

    // epilogue: write bf16 into padded interior + per-wave partial stats
    // cout = mi*16 + q*4 + g  ->  cc_out = mi>>1, ci = (mi&1)*16 + q*4 + g
    const int pbase = ((b * 128 + y0) * 2 + ph) * 64;
    #pragma unroll
    for (int mi = 0; mi < 4; ++mi) {
        float psum[4] = {0.f,0.f,0.f,0.f};
        float psq[4]  = {0.f,0.f,0.f,0.f};
        #pragma unroll
        for (int ni = 0; ni < 4; ++ni) {
            int xx = xb + ni * 16 + l15;
            size_t base = (size_t)b * PB + (size_t)(1 + y0) * PROW
                          + (mi >> 1) * 4160 + (size_t)(1 + xx) * 32
                          + (mi & 1) * 16 + q * 4;
            short4v o;
            #pragma unroll
            for (int g = 0; g < 4; ++g) {
                float v = acc[mi][ni][g];
                o[g] = f2bf(v);
                psum[g] += v;
                psq[g]  += v * v;
            }
            *(short4v*)&out[base] = o;
        }
        #pragma unroll
        for (int g = 0; g < 4; ++g) {
            float s = psum[g], s2 = psq[g];
            #pragma unroll
            for (int off = 1; off < 16; off <<= 1) {
                s  += __shfl_xor(s,  off, 64);
                s2 += __shfl_xor(s2, off, 64);
            }
            if (l15 == 0) {                       // 4 lanes (q=0..3), no contention
                int idx = pbase + mi * 16 + q * 4 + g;
                part_s[idx] = s;
                part_q[idx] = s2;
            }
        }
    }
}

// ---------------------------------------------------------------------------
// Reduce per-(row,pxhalf) partials -> (scale, bias) per (b,c). 1024 threads.
// ---------------------------------------------------------------------------
__global__ __launch_bounds__(256) void finalize_stats(const float* __restrict__ part_s,
                                                      const float* __restrict__ part_q,
                                                      float* __restrict__ nrm) {
    int i = blockIdx.x * 256 + threadIdx.x;
    if (i >= BATCH * CH) return;
    int b = i >> 6, c = i & 63;
    float s = 0.f, s2 = 0.f;
    const float* ps = part_s + (size_t)b * 128 * 2 * 64 + c;
    const float* pq = part_q + (size_t)b * 128 * 2 * 64 + c;
    #pragma unroll 4
    for (int r = 0; r < 256; ++r) {          // 128 rows x 2 pxhalves
        s  += ps[r * 64];
        s2 += pq[r * 64];
    }
    const float inv = 1.0f / (float)HW;
    float mean = s * inv;
    float var = s2 * inv - mean * mean;
    float scale = rsqrtf(var + 1e-5f);
    f32x2 sb = {scale, -mean * scale};
    ((f32x2*)nrm)[i] = sb;
}

// ---------------------------------------------------------------------------
// h = leaky(norm(y1)) IN PLACE on the padded buffer interior.
// ---------------------------------------------------------------------------
__global__ __launch_bounds__(256) void norm_leaky(short* __restrict__ hpad,
                                                  const float* __restrict__ nrm) {
    const int bid = blockIdx.x;
    const int b = bid >> 7, y = bid & 127;
    short* row = hpad + (size_t)b * PB + (size_t)(y + 1) * PROW;
    const int t = threadIdx.x;
    #pragma unroll
    for (int i = 0; i < 4; ++i) {
        int s = i * 256 + t;
        int c8 = s & 3, xx = (s >> 2) & 127, cc = s >> 9;
        short* p = row + cc * 4160 + (xx + 1) * 32 + c8 * 8;
        const f32x2* nb = (const f32x2*)nrm + b * CH + cc * 32 + c8 * 8;
        short8 v = *(const short8*)p;
        short8 o;
        #pragma unroll
        for (int j = 0; j < 8; ++j) {
            f32x2 sb = nb[j];
            float f = sb.x * bf2f(v[j]) + sb.y;
            f = f >= 0.f ? f : 0.2f * f;
            o[j] = f2bf(f);
        }
        *(short8*)p = o;
    }
}

// ---------------------------------------------------------------------------
// out = leaky(x + norm(y2)) : padded NHWC32 bf16 -> NCHW fp32, LDS transpose
// ---------------------------------------------------------------------------
__global__ __launch_bounds__(256) void final_kernel(const float* __restrict__ x,
                                                    const short* __restrict__ y2,
                                                    const float* __restrict__ nrm,
                                                    float* __restrict__ out) {
    __shared__ float tile[64 * 65];
    const int x0 = blockIdx.x * 64;
    const int y  = blockIdx.y;
    const int b  = blockIdx.z;
    const int t  = threadIdx.x;
    const f32x2* nb = (const f32x2*)nrm + b * CH;
    const size_t rowb = (size_t)b * PB + (size_t)(y + 1) * PROW;
    #pragma unroll
    for (int i = 0; i < 2; ++i) {
        int s = i * 256 + t;
        int xx = s >> 3;
        int c0 = (s & 7) * 8;
        int cc = c0 >> 5, cl = c0 & 31;
        short8 v = *(const short8*)&y2[rowb + cc * 4160 + (size_t)(x0 + xx + 1) * 32 + cl];
        #pragma unroll
        for (int j = 0; j < 8; ++j) {
            f32x2 sb = nb[c0 + j];
            tile[(c0 + j) * 65 + xx] = sb.x * bf2f(v[j]) + sb.y;
        }
    }
    __syncthreads();
    #pragma unroll
    for (int i = 0; i < 4; ++i) {
        int lin = i * 1024 + t * 4;
        int c = lin >> 6;
        int xx = lin & 63;
        size_t g = ((size_t)(b * CH + c) * IH + y) * IW + x0 + xx;
        f32x4 xv = *(const f32x4*)&x[g];
        f32x4 o;
        #pragma unroll
        for (int k = 0; k < 4; ++k) {
            float f = xv[k] + tile[c * 65 + xx + k];
            o[k] = f >= 0.f ? f : 0.2f * f;
        }
        *(f32x4*)&out[g] = o;
    }
}

// ---------------------------------------------------------------------------
extern "C" void kernel_launch(void* const* d_in, const int* in_sizes, int n_in,
                              void* d_out, int out_size, void* d_ws, size_t ws_size,
                              hipStream_t stream) {
    const float* x  = (const float*)d_in[0];
    const float* w1 = (const float*)d_in[1];
    const float* w2 = (const float*)d_in[2];
    float* out = (float*)d_out;
    char* ws = (char*)d_ws;

    const size_t SZ_PAD  = 34611200ull;        // one padded NHWC32 bf16 tensor
    const size_t SZ_PART = 1048576ull;         // 16*128*2*64 f32
    short* xpad = (short*)(ws);                // x (conv1 in), later y2 (conv2 out)
    short* hpad = (short*)(ws + SZ_PAD);       // y1 / h (conv1 out, conv2 in)
    short* w1t  = (short*)(ws + 2 * SZ_PAD);
    short* w2t  = (short*)(ws + 2 * SZ_PAD + 1179648ull);
    float* ps1  = (float*)(ws + 2 * SZ_PAD + 2359296ull);
    float* pq1  = (float*)(ws + 2 * SZ_PAD + 2359296ull + SZ_PART);
    float* ps2  = (float*)(ws + 2 * SZ_PAD + 2359296ull + 2 * SZ_PART);
    float* pq2  = (float*)(ws + 2 * SZ_PAD + 2359296ull + 3 * SZ_PART);
    float* nrm1 = (float*)(ws + 2 * SZ_PAD + 2359296ull + 4 * SZ_PART);
    float* nrm2 = nrm1 + BATCH * CH * 2;

    if (ws_size < 2 * SZ_PAD + 2359296ull + 4 * SZ_PART + 8192) return;

    pad_zero<<<32, 256, 0, stream>>>(xpad, hpad);
    prep_x<<<BATCH * IH, 256, 0, stream>>>(x, xpad);
    prep_w<<<512, 256, 0, stream>>>(w1, w2, w1t, w2t);
    conv_kernel<<<dim3(64, 16), 256, 0, stream>>>(xpad, w1t, hpad, ps1, pq1);
    finalize_stats<<<4, 256, 0, stream>>>(ps1, pq1, nrm1);
    norm_leaky<<<2048, 256, 0, stream>>>(hpad, nrm1);
    conv_kernel<<<dim3(64, 16), 256, 0, stream>>>(hpad, w2t, xpad, ps2, pq2);
    finalize_stats<<<4, 256, 0, stream>>>(ps2, pq2, nrm2);
    final_kernel<<<dim3(2, 128, 16), 256, 0, stream>>>(x, xpad, nrm2, out);
}

// Round 2
// 239.214 us; speedup vs baseline: 1.2002x; 1.2002x over previous
//
#include <hip/hip_runtime.h>
#include <stdint.h>
#include <stddef.h>

#define BATCH 16
#define CH    64
#define IH    128
#define IW    128
#define HW    (IH*IW)

// Padded activation layout: [b][yp 0..129][cc 0..1][xp 0..129][cin32]
#define PROW 8320            // shorts per padded row (2*130*32)
#define PB   1081600         // shorts per batch (130*PROW)

typedef __attribute__((ext_vector_type(8))) short short8;
typedef __attribute__((ext_vector_type(4))) short short4v;
typedef __attribute__((ext_vector_type(4))) float f32x4;
typedef __attribute__((ext_vector_type(2))) float f32x2;

__device__ __forceinline__ float bf2f(short s) {
    union { unsigned int u; float f; } v;
    v.u = ((unsigned int)(unsigned short)s) << 16;
    return v.f;
}
__device__ __forceinline__ short f2bf(float f) {
    union { float f; unsigned int u; } v; v.f = f;
    unsigned int r = v.u + 0x7fffu + ((v.u >> 16) & 1u);
    return (short)(r >> 16);
}

// async global->LDS: dest = lds_base + lane*16, src per-lane global addr
__device__ __forceinline__ void gload_lds16(const short* g, short* l) {
    __builtin_amdgcn_global_load_lds(
        (const __attribute__((address_space(1))) void*)g,
        (__attribute__((address_space(3))) void*)l, 16, 0, 0);
}

// ---------------------------------------------------------------------------
// Merged prep: blocks [0,2048) prep_x, [2048,2560) prep_w, [2560,2592) pad_zero
// ---------------------------------------------------------------------------
__global__ __launch_bounds__(256) void prep_all(const float* __restrict__ x,
                                                const float* __restrict__ w1,
                                                const float* __restrict__ w2,
                                                short* __restrict__ xpad,
                                                short* __restrict__ hpad,
                                                short* __restrict__ w1t,
                                                short* __restrict__ w2t) {
    const int bid = blockIdx.x;
    const int t = threadIdx.x;
    if (bid < 2048) {
        // ---- prep_x: x NCHW fp32 -> padded NHWC32 bf16 interior ----
        __shared__ float tile[CH * 129];
        const int b = bid >> 7;
        const int y = bid & 127;
        const float* src = x + (size_t)b * CH * HW + (size_t)y * IW;
        #pragma unroll
        for (int i = 0; i < 32; ++i) {
            int lin = i * 256 + t;
            int c = lin >> 7, xx = lin & 127;
            tile[c * 129 + xx] = src[(size_t)c * HW + xx];
        }
        __syncthreads();
        unsigned int* dst = (unsigned int*)(xpad) + (size_t)b * (PB / 2) + (size_t)(y + 1) * (PROW / 2);
        #pragma unroll
        for (int j = 0; j < 16; ++j) {
            int lin = j * 256 + t;
            int c2 = lin & 31, xx = lin >> 5;
            unsigned int lo = (unsigned int)(unsigned short)f2bf(tile[(2 * c2) * 129 + xx]);
            unsigned int hi = (unsigned int)(unsigned short)f2bf(tile[(2 * c2 + 1) * 129 + xx]);
            dst[(c2 >> 4) * 2080 + (xx + 1) * 16 + (c2 & 15)] = lo | (hi << 16);
        }
    } else if (bid < 2560) {
        // ---- prep_w: [b][co][ci][3][3] f32 -> [b][cc][tap][cout][cin32] bf16
        int b2 = bid - 2048;
        const float* src = w1; short* dst = w1t;
        if (b2 >= 256) { src = w2; dst = w2t; b2 -= 256; }
        int gt = b2 * 256 + t;
        int ci   = gt & 31;
        int cout = (gt >> 5) & 63;
        int cc   = (gt >> 11) & 1;
        int b    = gt >> 12;
        const float* s = src + ((size_t)(b * 64 + cout)) * 576 + (cc * 32 + ci) * 9;
        short* d = dst + ((size_t)(b * 2 + cc) * 9) * 2048 + cout * 32 + ci;
        #pragma unroll
        for (int tap = 0; tap < 9; ++tap)
            d[tap * 2048] = f2bf(s[tap]);
    } else {
        // ---- pad_zero: halo pads of both padded buffers ----
        int b2 = bid - 2560;
        short* p = ((b2 & 1) ? hpad : xpad) + (size_t)(b2 >> 1) * PB;
        const short8 z = {0,0,0,0,0,0,0,0};
        #pragma unroll
        for (int i = 0; i < 17; ++i) {
            int s = i * 256 + t;
            if (s >= 4128) break;
            if (s < 2080) {
                int row = (s < 1040) ? 0 : 129;
                int o = (s < 1040 ? s : s - 1040) * 8;
                *(short8*)&p[(size_t)row * PROW + o] = z;
            } else {
                int u = s - 2080;
                int k = u & 3, col = (u >> 2) & 1, cc = (u >> 3) & 1, pr = (u >> 4) + 1;
                *(short8*)&p[(size_t)pr * PROW + cc * 4160 + (col ? 129 * 32 : 0) + k * 8] = z;
            }
        }
    }
}

// ---------------------------------------------------------------------------
// Conv: LDS-staged implicit GEMM.
// Block = 4 waves = 2 output rows x 128 px x 64 cout.
// Stage: 4 padded input rows (66.5 KB) via global_load_lds, once per block.
// Compute: per (cc,tap) step, 4 weight loads (global, L1-broadcast across
// waves) + 8 ds_read_b128 feed 16 MFMAs. acc 4x4 f32x4 per wave.
// LDS 66.5KB -> 2 blocks/CU; __launch_bounds__(256,2) -> 256 VGPR cap for
// deep weight prefetch. grid dim3(64,16) = 1024 blocks = 2 rounds.
// ---------------------------------------------------------------------------
__global__ __launch_bounds__(256, 2) void conv_kernel(
    const short* __restrict__ in, const short* __restrict__ wt,
    short* __restrict__ out,
    float* __restrict__ part_s, float* __restrict__ part_q) {

    __shared__ short act[4 * PROW];          // 4 padded rows = 66,560 B

    const int b    = blockIdx.y;
    const int t    = threadIdx.x;
    const int lane = t & 63;
    const int wave = t >> 6;
    const int l15  = lane & 15;
    const int q    = lane >> 4;
    const int ph   = wave & 1;               // px half
    const int wr   = wave >> 1;              // output row within pair
    const int y0   = (blockIdx.x << 1) + wr;
    const int xb   = ph * 64;

    const short* inB = in + (size_t)b * PB;

    // ---- stage: wave w copies padded row (2*bx + w), 16,640 B ----
    {
        const short* grow = inB + (size_t)((blockIdx.x << 1) + wave) * PROW;
        short* lrow = &act[wave * PROW];
        #pragma unroll
        for (int i = 0; i < 16; ++i)
            gload_lds16(grow + i * 512 + lane * 8, lrow + i * 512);
        if (lane < 16)
            gload_lds16(grow + 16 * 512 + lane * 8, lrow + 16 * 512);
    }
    __syncthreads();                         // drains vmcnt before barrier

    const short* wgl = wt + (size_t)b * 36864;
    const int aoff = l15 * 32 + q * 8;
    const int boff = (xb + l15) * 32 + q * 8;

    const f32x4 zero4 = {0.f, 0.f, 0.f, 0.f};
    f32x4 acc[4][4];
    #pragma unroll
    for (int mi = 0; mi < 4; ++mi)
        #pragma unroll
        for (int ni = 0; ni < 4; ++ni) acc[mi][ni] = zero4;

    #pragma unroll
    for (int cc = 0; cc < 2; ++cc) {
        #pragma unroll
        for (int tap = 0; tap < 9; ++tap) {
            const int dy = tap / 3, dx = tap % 3;
            const short* arow = wgl + (cc * 9 + tap) * 2048 + aoff;
            const int bbase = (wr + dy) * PROW + cc * 4160 + dx * 32 + boff;
            short8 a[4], bb[4];
            #pragma unroll
            for (int mi = 0; mi < 4; ++mi)
                a[mi] = *(const short8*)&arow[mi * 512];
            #pragma unroll
            for (int ni = 0; ni < 4; ++ni)
                bb[ni] = *(const short8*)&act[bbase + ni * 512];
            #pragma unroll
            for (int mi = 0; mi < 4; ++mi)
                #pragma unroll
                for (int ni = 0; ni < 4; ++ni)
                    acc[mi][ni] = __builtin_amdgcn_mfma_f32_16x16x32_bf16(
                        a[mi], bb[ni], acc[mi][ni], 0, 0, 0);
        }
    }

    // epilogue: bf16 into padded interior + per-wave partial stats
    const int pbase = ((b * 128 + y0) * 2 + ph) * 64;
    #pragma unroll
    for (int mi = 0; mi < 4; ++mi) {
        float psum[4] = {0.f,0.f,0.f,0.f};
        float psq[4]  = {0.f,0.f,0.f,0.f};
        #pragma unroll
        for (int ni = 0; ni < 4; ++ni) {
            int xx = xb + ni * 16 + l15;
            size_t base = (size_t)b * PB + (size_t)(1 + y0) * PROW
                          + (mi >> 1) * 4160 + (size_t)(1 + xx) * 32
                          + (mi & 1) * 16 + q * 4;
            short4v o;
            #pragma unroll
            for (int g = 0; g < 4; ++g) {
                float v = acc[mi][ni][g];
                o[g] = f2bf(v);
                psum[g] += v;
                psq[g]  += v * v;
            }
            *(short4v*)&out[base] = o;
        }
        #pragma unroll
        for (int g = 0; g < 4; ++g) {
            float s = psum[g], s2 = psq[g];
            #pragma unroll
            for (int off = 1; off < 16; off <<= 1) {
                s  += __shfl_xor(s,  off, 64);
                s2 += __shfl_xor(s2, off, 64);
            }
            if (l15 == 0) {
                int idx = pbase + mi * 16 + q * 4 + g;
                part_s[idx] = s;
                part_q[idx] = s2;
            }
        }
    }
}

// ---------------------------------------------------------------------------
// Reduce per-(row,pxhalf) partials -> (scale, bias) per (b,c).
// 16 blocks (one per b); 256 threads = 64 c x 4 row-groups; LDS tree.
// ---------------------------------------------------------------------------
__global__ __launch_bounds__(256) void finalize_stats(const float* __restrict__ part_s,
                                                      const float* __restrict__ part_q,
                                                      float* __restrict__ nrm) {
    __shared__ float red[2][4][64];
    const int b = blockIdx.x;
    const int c = threadIdx.x & 63;
    const int g = threadIdx.x >> 6;
    const float* ps = part_s + (size_t)b * 16384 + c;
    const float* pq = part_q + (size_t)b * 16384 + c;
    float s = 0.f, s2 = 0.f;
    #pragma unroll 8
    for (int r = 0; r < 64; ++r) {
        s  += ps[(g * 64 + r) * 64];
        s2 += pq[(g * 64 + r) * 64];
    }
    red[0][g][c] = s;
    red[1][g][c] = s2;
    __syncthreads();
    if (threadIdx.x < 64) {
        float S = red[0][0][c] + red[0][1][c] + red[0][2][c] + red[0][3][c];
        float Q = red[1][0][c] + red[1][1][c] + red[1][2][c] + red[1][3][c];
        const float inv = 1.0f / (float)HW;
        float mean = S * inv;
        float var = Q * inv - mean * mean;
        float scale = rsqrtf(var + 1e-5f);
        f32x2 sb = {scale, -mean * scale};
        ((f32x2*)nrm)[b * CH + c] = sb;
    }
}

// ---------------------------------------------------------------------------
// h = leaky(norm(y1)) IN PLACE on the padded buffer interior.
// ---------------------------------------------------------------------------
__global__ __launch_bounds__(256) void norm_leaky(short* __restrict__ hpad,
                                                  const float* __restrict__ nrm) {
    const int bid = blockIdx.x;
    const int b = bid >> 7, y = bid & 127;
    short* row = hpad + (size_t)b * PB + (size_t)(y + 1) * PROW;
    const int t = threadIdx.x;
    #pragma unroll
    for (int i = 0; i < 4; ++i) {
        int s = i * 256 + t;
        int c8 = s & 3, xx = (s >> 2) & 127, cc = s >> 9;
        short* p = row + cc * 4160 + (xx + 1) * 32 + c8 * 8;
        const f32x2* nb = (const f32x2*)nrm + b * CH + cc * 32 + c8 * 8;
        short8 v = *(const short8*)p;
        short8 o;
        #pragma unroll
        for (int j = 0; j < 8; ++j) {
            f32x2 sb = nb[j];
            float f = sb.x * bf2f(v[j]) + sb.y;
            f = f >= 0.f ? f : 0.2f * f;
            o[j] = f2bf(f);
        }
        *(short8*)p = o;
    }
}

// ---------------------------------------------------------------------------
// out = leaky(x + norm(y2)) : padded NHWC32 bf16 -> NCHW fp32, LDS transpose
// ---------------------------------------------------------------------------
__global__ __launch_bounds__(256) void final_kernel(const float* __restrict__ x,
                                                    const short* __restrict__ y2,
                                                    const float* __restrict__ nrm,
                                                    float* __restrict__ out) {
    __shared__ float tile[64 * 65];
    const int x0 = blockIdx.x * 64;
    const int y  = blockIdx.y;
    const int b  = blockIdx.z;
    const int t  = threadIdx.x;
    const f32x2* nb = (const f32x2*)nrm + b * CH;
    const size_t rowb = (size_t)b * PB + (size_t)(y + 1) * PROW;
    #pragma unroll
    for (int i = 0; i < 2; ++i) {
        int s = i * 256 + t;
        int xx = s >> 3;
        int c0 = (s & 7) * 8;
        int cc = c0 >> 5, cl = c0 & 31;
        short8 v = *(const short8*)&y2[rowb + cc * 4160 + (size_t)(x0 + xx + 1) * 32 + cl];
        #pragma unroll
        for (int j = 0; j < 8; ++j) {
            f32x2 sb = nb[c0 + j];
            tile[(c0 + j) * 65 + xx] = sb.x * bf2f(v[j]) + sb.y;
        }
    }
    __syncthreads();
    #pragma unroll
    for (int i = 0; i < 4; ++i) {
        int lin = i * 1024 + t * 4;
        int c = lin >> 6;
        int xx = lin & 63;
        size_t g = ((size_t)(b * CH + c) * IH + y) * IW + x0 + xx;
        f32x4 xv = *(const f32x4*)&x[g];
        f32x4 o;
        #pragma unroll
        for (int k = 0; k < 4; ++k) {
            float f = xv[k] + tile[c * 65 + xx + k];
            o[k] = f >= 0.f ? f : 0.2f * f;
        }
        *(f32x4*)&out[g] = o;
    }
}

// ---------------------------------------------------------------------------
extern "C" void kernel_launch(void* const* d_in, const int* in_sizes, int n_in,
                              void* d_out, int out_size, void* d_ws, size_t ws_size,
                              hipStream_t stream) {
    const float* x  = (const float*)d_in[0];
    const float* w1 = (const float*)d_in[1];
    const float* w2 = (const float*)d_in[2];
    float* out = (float*)d_out;
    char* ws = (char*)d_ws;

    const size_t SZ_PAD  = 34611200ull;        // one padded NHWC32 bf16 tensor
    const size_t SZ_PART = 1048576ull;         // 16*128*2*64 f32
    short* xpad = (short*)(ws);                // x (conv1 in), later y2 (conv2 out)
    short* hpad = (short*)(ws + SZ_PAD);       // y1 / h (conv1 out, conv2 in)
    short* w1t  = (short*)(ws + 2 * SZ_PAD);
    short* w2t  = (short*)(ws + 2 * SZ_PAD + 1179648ull);
    float* ps1  = (float*)(ws + 2 * SZ_PAD + 2359296ull);
    float* pq1  = (float*)(ws + 2 * SZ_PAD + 2359296ull + SZ_PART);
    float* ps2  = (float*)(ws + 2 * SZ_PAD + 2359296ull + 2 * SZ_PART);
    float* pq2  = (float*)(ws + 2 * SZ_PAD + 2359296ull + 3 * SZ_PART);
    float* nrm1 = (float*)(ws + 2 * SZ_PAD + 2359296ull + 4 * SZ_PART);
    float* nrm2 = nrm1 + BATCH * CH * 2;

    if (ws_size < 2 * SZ_PAD + 2359296ull + 4 * SZ_PART + 8192) return;

    prep_all<<<2592, 256, 0, stream>>>(x, w1, w2, xpad, hpad, w1t, w2t);
    conv_kernel<<<dim3(64, 16), 256, 0, stream>>>(xpad, w1t, hpad, ps1, pq1);
    finalize_stats<<<16, 256, 0, stream>>>(ps1, pq1, nrm1);
    norm_leaky<<<2048, 256, 0, stream>>>(hpad, nrm1);
    conv_kernel<<<dim3(64, 16), 256, 0, stream>>>(hpad, w2t, xpad, ps2, pq2);
    finalize_stats<<<16, 256, 0, stream>>>(ps2, pq2, nrm2);
    final_kernel<<<dim3(2, 128, 16), 256, 0, stream>>>(x, xpad, nrm2, out);
}

// Round 3
// 230.968 us; speedup vs baseline: 1.2431x; 1.0357x over previous
//
#include <hip/hip_runtime.h>
#include <stdint.h>
#include <stddef.h>

#define BATCH 16
#define CH    64
#define IH    128
#define IW    128
#define HW    (IH*IW)

// Padded activation layout: [b][yp 0..129][cc 0..1][xp 0..129][cin32]
#define PROW 8320            // shorts per padded row (2*130*32)
#define PB   1081600         // shorts per batch (130*PROW)
#define SEG  2112            // shorts per staged segment: 66 px x 32 ci

typedef __attribute__((ext_vector_type(8))) short short8;
typedef __attribute__((ext_vector_type(4))) short short4v;
typedef __attribute__((ext_vector_type(4))) float f32x4;
typedef __attribute__((ext_vector_type(2))) float f32x2;

__device__ __forceinline__ float bf2f(short s) {
    union { unsigned int u; float f; } v;
    v.u = ((unsigned int)(unsigned short)s) << 16;
    return v.f;
}
__device__ __forceinline__ short f2bf(float f) {
    union { float f; unsigned int u; } v; v.f = f;
    unsigned int r = v.u + 0x7fffu + ((v.u >> 16) & 1u);
    return (short)(r >> 16);
}

// async global->LDS: dest = lds_base + lane*16, src per-lane global addr
__device__ __forceinline__ void gload_lds16(const short* g, short* l) {
    __builtin_amdgcn_global_load_lds(
        (const __attribute__((address_space(1))) void*)g,
        (__attribute__((address_space(3))) void*)l, 16, 0, 0);
}

// ---------------------------------------------------------------------------
// Merged prep: blocks [0,2048) prep_x, [2048,2560) prep_w, [2560,2576) pad_zero
// (only xpad needs its halo zeroed: conv1 stages it via global_load_lds;
//  conv2's fused stage masks hpad halos itself.)
// ---------------------------------------------------------------------------
__global__ __launch_bounds__(256) void prep_all(const float* __restrict__ x,
                                                const float* __restrict__ w1,
                                                const float* __restrict__ w2,
                                                short* __restrict__ xpad,
                                                short* __restrict__ w1t,
                                                short* __restrict__ w2t) {
    const int bid = blockIdx.x;
    const int t = threadIdx.x;
    if (bid < 2048) {
        // ---- prep_x: x NCHW fp32 -> padded NHWC32 bf16 interior ----
        __shared__ float tile[CH * 129];
        const int b = bid >> 7;
        const int y = bid & 127;
        const float* src = x + (size_t)b * CH * HW + (size_t)y * IW;
        #pragma unroll
        for (int i = 0; i < 32; ++i) {
            int lin = i * 256 + t;
            int c = lin >> 7, xx = lin & 127;
            tile[c * 129 + xx] = src[(size_t)c * HW + xx];
        }
        __syncthreads();
        unsigned int* dst = (unsigned int*)(xpad) + (size_t)b * (PB / 2) + (size_t)(y + 1) * (PROW / 2);
        #pragma unroll
        for (int j = 0; j < 16; ++j) {
            int lin = j * 256 + t;
            int c2 = lin & 31, xx = lin >> 5;
            unsigned int lo = (unsigned int)(unsigned short)f2bf(tile[(2 * c2) * 129 + xx]);
            unsigned int hi = (unsigned int)(unsigned short)f2bf(tile[(2 * c2 + 1) * 129 + xx]);
            dst[(c2 >> 4) * 2080 + (xx + 1) * 16 + (c2 & 15)] = lo | (hi << 16);
        }
    } else if (bid < 2560) {
        // ---- prep_w: [b][co][ci][3][3] f32 -> [b][cc][tap][cout][cin32] bf16
        int b2 = bid - 2048;
        const float* src = w1; short* dst = w1t;
        if (b2 >= 256) { src = w2; dst = w2t; b2 -= 256; }
        int gt = b2 * 256 + t;
        int ci   = gt & 31;
        int cout = (gt >> 5) & 63;
        int cc   = (gt >> 11) & 1;
        int b    = gt >> 12;
        const float* s = src + ((size_t)(b * 64 + cout)) * 576 + (cc * 32 + ci) * 9;
        short* d = dst + ((size_t)(b * 2 + cc) * 9) * 2048 + cout * 32 + ci;
        #pragma unroll
        for (int tap = 0; tap < 9; ++tap)
            d[tap * 2048] = f2bf(s[tap]);
    } else {
        // ---- pad_zero: halo of xpad only ----
        int b2 = bid - 2560;
        short* p = xpad + (size_t)b2 * PB;
        const short8 z = {0,0,0,0,0,0,0,0};
        #pragma unroll
        for (int i = 0; i < 17; ++i) {
            int s = i * 256 + t;
            if (s >= 4128) break;
            if (s < 2080) {
                int row = (s < 1040) ? 0 : 129;
                int o = (s < 1040 ? s : s - 1040) * 8;
                *(short8*)&p[(size_t)row * PROW + o] = z;
            } else {
                int u = s - 2080;
                int k = u & 3, col = (u >> 2) & 1, cc = (u >> 3) & 1, pr = (u >> 4) + 1;
                *(short8*)&p[(size_t)pr * PROW + cc * 4160 + (col ? 129 * 32 : 0) + k * 8] = z;
            }
        }
    }
}

// ---------------------------------------------------------------------------
// Conv: LDS-staged implicit GEMM, 3 blocks/CU.
// Block = 4 waves = 4 output rows x 64 px x 64 cout (wave wr = one row).
// Staged window: 6 padded rows x 66 px x 2cc = 12 segments of 2112 shorts
// = 50,688 B LDS. Per (cc,tap) step per wave: 4 A global loads (distance-1
// register prefetch pipeline) + 4 ds_read_b128 feed 16 MFMAs, acc 4x4.
// FUSED variant (conv2): reg-staged y1 -> norm+leaky -> ds_write (halos
// masked to zero), eliminating the separate norm_leaky pass.
// grid dim3(64,16) = 1024 blocks; __launch_bounds__(256,3).
// ---------------------------------------------------------------------------
template<bool FUSED>
__global__ __launch_bounds__(256, 3) void conv_kernel(
    const short* __restrict__ in, const short* __restrict__ wt,
    short* __restrict__ out, const float* __restrict__ nrm,
    float* __restrict__ part_s, float* __restrict__ part_q) {

    __shared__ short act[12 * SEG];          // 50,688 B

    const int b    = blockIdx.y;
    const int t    = threadIdx.x;
    const int lane = t & 63;
    const int wave = t >> 6;                 // wr: output row within quad
    const int l15  = lane & 15;
    const int q    = lane >> 4;
    const int bx   = blockIdx.x >> 1;
    const int ph2  = blockIdx.x & 1;         // px half
    const int xp0  = ph2 * 64;               // staged x start (padded coords)
    const int y0   = bx * 4 + wave;          // this wave's output row

    const short* inB = in + (size_t)b * PB;
    const short* wgl = wt + (size_t)b * 36864;
    const int aoff = l15 * 32 + q * 8;

    // ---- A pipeline prologue: weights for step 0 (hide under stage) ----
    short8 a2[2][4];
    #pragma unroll
    for (int mi = 0; mi < 4; ++mi)
        a2[0][mi] = *(const short8*)&wgl[aoff + mi * 512];

    // ---- stage: wave handles segments {wave, wave+4, wave+8} ----
    // seg s = (r = s>>1, cc = s&1); cc = wave&1 is wave-uniform.
    if (!FUSED) {
        #pragma unroll
        for (int k = 0; k < 3; ++k) {
            const int s = wave + k * 4;
            const int rg = bx * 4 + (s >> 1);
            const short* gseg = inB + (size_t)rg * PROW + (s & 1) * 4160 + xp0 * 32;
            short* lseg = &act[s * SEG];
            #pragma unroll
            for (int c = 0; c < 4; ++c)
                gload_lds16(gseg + c * 512 + lane * 8, lseg + c * 512);
            if (lane < 8)
                gload_lds16(gseg + 2048 + lane * 8, lseg + 2048);
        }
    } else {
        const int scc = wave & 1;            // this wave's cc (uniform)
        const int ci0 = (lane & 3) * 8;
        f32x2 sb[8];
        #pragma unroll
        for (int j = 0; j < 8; ++j)
            sb[j] = ((const f32x2*)nrm)[b * CH + scc * 32 + ci0 + j];
        #pragma unroll
        for (int k = 0; k < 3; ++k) {
            const int s = wave + k * 4;
            const int rg = bx * 4 + (s >> 1);
            const bool rowpad = (rg == 0) || (rg == 129);
            const short* gseg = inB + (size_t)rg * PROW + scc * 4160 + xp0 * 32;
            short* lseg = &act[s * SEG];
            #pragma unroll
            for (int c = 0; c < 5; ++c) {
                if (c < 4 || lane < 8) {
                    short8 v = *(const short8*)&gseg[c * 512 + lane * 8];
                    const int lpx = c * 16 + (lane >> 2);
                    const bool xm = (ph2 == 0 && lpx == 0) || (ph2 == 1 && lpx == 65);
                    short8 o;
                    if (rowpad || xm) {
                        o = (short8){0,0,0,0,0,0,0,0};
                    } else {
                        #pragma unroll
                        for (int j = 0; j < 8; ++j) {
                            float f = sb[j].x * bf2f(v[j]) + sb[j].y;
                            f = f >= 0.f ? f : 0.2f * f;
                            o[j] = f2bf(f);
                        }
                    }
                    *(short8*)&lseg[c * 512 + lane * 8] = o;
                }
            }
        }
    }
    __syncthreads();

    const f32x4 zero4 = {0.f, 0.f, 0.f, 0.f};
    f32x4 acc[4][4];
    #pragma unroll
    for (int mi = 0; mi < 4; ++mi)
        #pragma unroll
        for (int ni = 0; ni < 4; ++ni) acc[mi][ni] = zero4;

    #pragma unroll
    for (int s = 0; s < 18; ++s) {           // s = cc*9 + tap
        const int cc = s / 9, tap = s % 9;
        const int dy = tap / 3, dx = tap % 3;
        // distance-1 weight prefetch (compile-time slot index)
        if (s + 1 < 18) {
            const short* anext = wgl + (s + 1) * 2048 + aoff;
            #pragma unroll
            for (int mi = 0; mi < 4; ++mi)
                a2[(s + 1) & 1][mi] = *(const short8*)&anext[mi * 512];
        }
        const int segb = ((wave + dy) * 2 + cc) * SEG;
        short8 bb[4];
        #pragma unroll
        for (int ni = 0; ni < 4; ++ni)
            bb[ni] = *(const short8*)&act[segb + (dx + ni * 16 + l15) * 32 + q * 8];
        #pragma unroll
        for (int mi = 0; mi < 4; ++mi)
            #pragma unroll
            for (int ni = 0; ni < 4; ++ni)
                acc[mi][ni] = __builtin_amdgcn_mfma_f32_16x16x32_bf16(
                    a2[s & 1][mi], bb[ni], acc[mi][ni], 0, 0, 0);
    }

    // epilogue: bf16 into padded interior + per-wave partial stats
    const int pbase = ((b * 128 + y0) * 2 + ph2) * 64;
    #pragma unroll
    for (int mi = 0; mi < 4; ++mi) {
        float psum[4] = {0.f,0.f,0.f,0.f};
        float psq[4]  = {0.f,0.f,0.f,0.f};
        #pragma unroll
        for (int ni = 0; ni < 4; ++ni) {
            int xx = xp0 + ni * 16 + l15;
            size_t base = (size_t)b * PB + (size_t)(1 + y0) * PROW
                          + (mi >> 1) * 4160 + (size_t)(1 + xx) * 32
                          + (mi & 1) * 16 + q * 4;
            short4v o;
            #pragma unroll
            for (int g = 0; g < 4; ++g) {
                float v = acc[mi][ni][g];
                o[g] = f2bf(v);
                psum[g] += v;
                psq[g]  += v * v;
            }
            *(short4v*)&out[base] = o;
        }
        #pragma unroll
        for (int g = 0; g < 4; ++g) {
            float s = psum[g], s2 = psq[g];
            #pragma unroll
            for (int off = 1; off < 16; off <<= 1) {
                s  += __shfl_xor(s,  off, 64);
                s2 += __shfl_xor(s2, off, 64);
            }
            if (l15 == 0) {
                int idx = pbase + mi * 16 + q * 4 + g;
                part_s[idx] = s;
                part_q[idx] = s2;
            }
        }
    }
}

// ---------------------------------------------------------------------------
// Reduce per-(row,pxhalf) partials -> (scale, bias) per (b,c).
// ---------------------------------------------------------------------------
__global__ __launch_bounds__(256) void finalize_stats(const float* __restrict__ part_s,
                                                      const float* __restrict__ part_q,
                                                      float* __restrict__ nrm) {
    __shared__ float red[2][4][64];
    const int b = blockIdx.x;
    const int c = threadIdx.x & 63;
    const int g = threadIdx.x >> 6;
    const float* ps = part_s + (size_t)b * 16384 + c;
    const float* pq = part_q + (size_t)b * 16384 + c;
    float s = 0.f, s2 = 0.f;
    #pragma unroll 8
    for (int r = 0; r < 64; ++r) {
        s  += ps[(g * 64 + r) * 64];
        s2 += pq[(g * 64 + r) * 64];
    }
    red[0][g][c] = s;
    red[1][g][c] = s2;
    __syncthreads();
    if (threadIdx.x < 64) {
        float S = red[0][0][c] + red[0][1][c] + red[0][2][c] + red[0][3][c];
        float Q = red[1][0][c] + red[1][1][c] + red[1][2][c] + red[1][3][c];
        const float inv = 1.0f / (float)HW;
        float mean = S * inv;
        float var = Q * inv - mean * mean;
        float scale = rsqrtf(var + 1e-5f);
        f32x2 sb = {scale, -mean * scale};
        ((f32x2*)nrm)[b * CH + c] = sb;
    }
}

// ---------------------------------------------------------------------------
// out = leaky(x + norm(y2)) : padded NHWC32 bf16 -> NCHW fp32, LDS transpose
// ---------------------------------------------------------------------------
__global__ __launch_bounds__(256) void final_kernel(const float* __restrict__ x,
                                                    const short* __restrict__ y2,
                                                    const float* __restrict__ nrm,
                                                    float* __restrict__ out) {
    __shared__ float tile[64 * 65];
    const int x0 = blockIdx.x * 64;
    const int y  = blockIdx.y;
    const int b  = blockIdx.z;
    const int t  = threadIdx.x;
    const f32x2* nb = (const f32x2*)nrm + b * CH;
    const size_t rowb = (size_t)b * PB + (size_t)(y + 1) * PROW;
    #pragma unroll
    for (int i = 0; i < 2; ++i) {
        int s = i * 256 + t;
        int xx = s >> 3;
        int c0 = (s & 7) * 8;
        int cc = c0 >> 5, cl = c0 & 31;
        short8 v = *(const short8*)&y2[rowb + cc * 4160 + (size_t)(x0 + xx + 1) * 32 + cl];
        #pragma unroll
        for (int j = 0; j < 8; ++j) {
            f32x2 sb = nb[c0 + j];
            tile[(c0 + j) * 65 + xx] = sb.x * bf2f(v[j]) + sb.y;
        }
    }
    __syncthreads();
    #pragma unroll
    for (int i = 0; i < 4; ++i) {
        int lin = i * 1024 + t * 4;
        int c = lin >> 6;
        int xx = lin & 63;
        size_t g = ((size_t)(b * CH + c) * IH + y) * IW + x0 + xx;
        f32x4 xv = *(const f32x4*)&x[g];
        f32x4 o;
        #pragma unroll
        for (int k = 0; k < 4; ++k) {
            float f = xv[k] + tile[c * 65 + xx + k];
            o[k] = f >= 0.f ? f : 0.2f * f;
        }
        *(f32x4*)&out[g] = o;
    }
}

// ---------------------------------------------------------------------------
extern "C" void kernel_launch(void* const* d_in, const int* in_sizes, int n_in,
                              void* d_out, int out_size, void* d_ws, size_t ws_size,
                              hipStream_t stream) {
    const float* x  = (const float*)d_in[0];
    const float* w1 = (const float*)d_in[1];
    const float* w2 = (const float*)d_in[2];
    float* out = (float*)d_out;
    char* ws = (char*)d_ws;

    const size_t SZ_PAD  = 34611200ull;        // one padded NHWC32 bf16 tensor
    const size_t SZ_PART = 1048576ull;         // 16*128*2*64 f32
    short* xpad = (short*)(ws);                // x (conv1 in), later y2 (conv2 out)
    short* hpad = (short*)(ws + SZ_PAD);       // y1 raw (conv1 out, conv2 in)
    short* w1t  = (short*)(ws + 2 * SZ_PAD);
    short* w2t  = (short*)(ws + 2 * SZ_PAD + 1179648ull);
    float* ps1  = (float*)(ws + 2 * SZ_PAD + 2359296ull);
    float* pq1  = (float*)(ws + 2 * SZ_PAD + 2359296ull + SZ_PART);
    float* ps2  = (float*)(ws + 2 * SZ_PAD + 2359296ull + 2 * SZ_PART);
    float* pq2  = (float*)(ws + 2 * SZ_PAD + 2359296ull + 3 * SZ_PART);
    float* nrm1 = (float*)(ws + 2 * SZ_PAD + 2359296ull + 4 * SZ_PART);
    float* nrm2 = nrm1 + BATCH * CH * 2;

    if (ws_size < 2 * SZ_PAD + 2359296ull + 4 * SZ_PART + 8192) return;

    prep_all<<<2576, 256, 0, stream>>>(x, w1, w2, xpad, w1t, w2t);
    conv_kernel<false><<<dim3(64, 16), 256, 0, stream>>>(xpad, w1t, hpad, nullptr, ps1, pq1);
    finalize_stats<<<16, 256, 0, stream>>>(ps1, pq1, nrm1);
    conv_kernel<true><<<dim3(64, 16), 256, 0, stream>>>(hpad, w2t, xpad, nrm1, ps2, pq2);
    finalize_stats<<<16, 256, 0, stream>>>(ps2, pq2, nrm2);
    final_kernel<<<dim3(2, 128, 16), 256, 0, stream>>>(x, xpad, nrm2, out);
}